// Round 5
// baseline (197.189 us; speedup 1.0000x reference)
//
#include <hip/hip_runtime.h>
#include <hip/hip_bf16.h>

typedef __bf16 bf16;
typedef __bf16 bf16x8 __attribute__((ext_vector_type(8)));
typedef float f32x4 __attribute__((ext_vector_type(4)));

#define B_ 8
#define N_ 1024
#define C_ 256
#define H_ 8
#define C3_ 768
#define SCALE 0.17677669529663689f  // 1/sqrt(32)
#define FMAX 16.0f                  // fixed softmax max; scores ~N(0,1), margin huge

// ---------------------------------------------------------------------------
// QKV projection. A = X [8192,256] fp32, Bm = W_qkv [256,768] fp32.
// fp32->bf16 during LDS staging; bf16 MFMA, fp32 accum. Software-pipelined:
// next k-tile's global loads issued before the MFMA section.
// cols 0..511 (q,k) -> qk[row*512+col]; cols 512..767 (v) -> vT transposed.
// ---------------------------------------------------------------------------
__global__ __launch_bounds__(256) void gemm_qkv(
    const float* __restrict__ A, const float* __restrict__ Bm,
    bf16* __restrict__ qk, bf16* __restrict__ vT)
{
  __shared__ bf16 As[64][40];
  __shared__ bf16 Bts[64][40];  // B transposed: Bts[n][k]

  int tid = threadIdx.x;
  int wave = tid >> 6, lane = tid & 63, quad = lane >> 4, l16 = lane & 15;
  int m0 = blockIdx.x * 64, n0 = blockIdx.y * 64;
  int msub = (wave & 1) * 32, nsub = (wave >> 1) * 32;

  f32x4 acc[2][2] = {};

  int arow = tid >> 2, akc = (tid & 3) * 8;  // A stage: 64 rows x 32 k
  int bk = tid >> 3, bn8 = (tid & 7) * 8;    // B stage: 32 k x 64 n

  const float* aptr = A + (long)(m0 + arow) * C_ + akc;
  const float* bptr = Bm + (long)bk * C3_ + n0 + bn8;

  // pipeline preload k0 = 0
  float4 a0 = *reinterpret_cast<const float4*>(aptr);
  float4 a1 = *reinterpret_cast<const float4*>(aptr + 4);
  float4 b0 = *reinterpret_cast<const float4*>(bptr);
  float4 b1 = *reinterpret_cast<const float4*>(bptr + 4);

  for (int k0 = 0; k0 < C_; k0 += 32) {
    __syncthreads();  // protect LDS from previous iteration's readers
    bf16 at[8] = {(bf16)a0.x, (bf16)a0.y, (bf16)a0.z, (bf16)a0.w,
                  (bf16)a1.x, (bf16)a1.y, (bf16)a1.z, (bf16)a1.w};
    *reinterpret_cast<bf16x8*>(&As[arow][akc]) = *reinterpret_cast<bf16x8*>(at);
    Bts[bn8 + 0][bk] = (bf16)b0.x; Bts[bn8 + 1][bk] = (bf16)b0.y;
    Bts[bn8 + 2][bk] = (bf16)b0.z; Bts[bn8 + 3][bk] = (bf16)b0.w;
    Bts[bn8 + 4][bk] = (bf16)b1.x; Bts[bn8 + 5][bk] = (bf16)b1.y;
    Bts[bn8 + 6][bk] = (bf16)b1.z; Bts[bn8 + 7][bk] = (bf16)b1.w;
    __syncthreads();

    int kn = k0 + 32;
    if (kn < C_) {  // uniform branch: prefetch next k-tile
      a0 = *reinterpret_cast<const float4*>(aptr + kn);
      a1 = *reinterpret_cast<const float4*>(aptr + kn + 4);
      b0 = *reinterpret_cast<const float4*>(bptr + (long)kn * C3_);
      b1 = *reinterpret_cast<const float4*>(bptr + (long)kn * C3_ + 4);
    }

    bf16x8 af0 = *reinterpret_cast<const bf16x8*>(&As[msub + l16][quad * 8]);
    bf16x8 af1 = *reinterpret_cast<const bf16x8*>(&As[msub + 16 + l16][quad * 8]);
    bf16x8 bfr0 = *reinterpret_cast<const bf16x8*>(&Bts[nsub + l16][quad * 8]);
    bf16x8 bfr1 = *reinterpret_cast<const bf16x8*>(&Bts[nsub + 16 + l16][quad * 8]);
    acc[0][0] = __builtin_amdgcn_mfma_f32_16x16x32_bf16(af0, bfr0, acc[0][0], 0, 0, 0);
    acc[0][1] = __builtin_amdgcn_mfma_f32_16x16x32_bf16(af0, bfr1, acc[0][1], 0, 0, 0);
    acc[1][0] = __builtin_amdgcn_mfma_f32_16x16x32_bf16(af1, bfr0, acc[1][0], 0, 0, 0);
    acc[1][1] = __builtin_amdgcn_mfma_f32_16x16x32_bf16(af1, bfr1, acc[1][1], 0, 0, 0);
  }

#pragma unroll
  for (int mi = 0; mi < 2; ++mi)
#pragma unroll
    for (int ni = 0; ni < 2; ++ni)
#pragma unroll
      for (int r = 0; r < 4; ++r) {
        int row = m0 + msub + mi * 16 + quad * 4 + r;  // C layout: row=quad*4+reg
        int col = n0 + nsub + ni * 16 + l16;           // col=lane&15
        float v = acc[mi][ni][r];
        if (col < 512) {
          qk[(long)row * 512 + col] = (bf16)v;
        } else {
          int b = row >> 10, n = row & 1023;
          vT[((long)(b * C_ + (col - 512))) * N_ + n] = (bf16)v;
        }
      }
}

// ---------------------------------------------------------------------------
// Flash attention, fixed-max softmax, software-pipelined. Block = (16-row
// i-tile, b); 512 threads, one wave per head -> each rel tile fetched once.
// K/V/rel for tile j+1 prefetched into registers before tile j's exp/PV
// section, hiding HBM latency. P via wave-private LDS (lgkmcnt drain only).
// ---------------------------------------------------------------------------
__global__ __launch_bounds__(512) void flash_attn(
    const bf16* __restrict__ qk, const bf16* __restrict__ vT,
    const int* __restrict__ rel, const int* __restrict__ rel_len,
    const float* __restrict__ btab, float* __restrict__ att)
{
  __shared__ bf16 Pls[H_][16 * 40];
  __shared__ float btl[H_][16];

  int tid = threadIdx.x;
  int h = tid >> 6, lane = tid & 63, quad = lane >> 4, l16 = lane & 15;
  int b = blockIdx.y, i0 = blockIdx.x * 16;

  int mask_len = (int)((float)rel_len[b] * 0.5f);
  if (tid < 80) {
    int t = tid >> 3, hh = tid & 7;
    btl[hh][t] = btab[t * H_ + hh] + (t > mask_len ? -100.f : 0.f);
  }
  __syncthreads();

  long bN = (long)b * N_;
  bf16x8 qf = *reinterpret_cast<const bf16x8*>(
      qk + (bN + i0 + l16) * 512 + h * 32 + quad * 8);

  const bf16* kb = qk + bN * 512 + 256 + h * 32 + quad * 8;          // + j*512
  const bf16* vb0 = vT + (long)(b * C_ + h * 32 + l16) * N_ + quad * 8;  // + j
  const bf16* vb1 = vb0 + 16 * N_;
  const int* relr = rel + (bN + i0 + quad * 4) * N_ + l16;           // + r*N + j

  f32x4 oacc[2] = {};
  float l_part[4] = {0.f, 0.f, 0.f, 0.f};

  // pipeline preload for j0 = 0
  bf16x8 kf0 = *reinterpret_cast<const bf16x8*>(kb + (long)l16 * 512);
  bf16x8 kf1 = *reinterpret_cast<const bf16x8*>(kb + (long)(16 + l16) * 512);
  bf16x8 vf0 = *reinterpret_cast<const bf16x8*>(vb0);
  bf16x8 vf1 = *reinterpret_cast<const bf16x8*>(vb1);
  int rv[8];
#pragma unroll
  for (int r = 0; r < 4; ++r) {
    rv[r]     = relr[(long)r * N_];
    rv[4 + r] = relr[(long)r * N_ + 16];
  }

  for (int j0 = 0; j0 < N_; j0 += 32) {
    f32x4 z = {};
    f32x4 s0 = __builtin_amdgcn_mfma_f32_16x16x32_bf16(qf, kf0, z, 0, 0, 0);
    f32x4 s1 = __builtin_amdgcn_mfma_f32_16x16x32_bf16(qf, kf1, z, 0, 0, 0);

    // prefetch next tile (clamped to 0 on last iter; values then unused)
    int jn = j0 + 32; jn = (jn < N_) ? jn : 0;
    bf16x8 kn0 = *reinterpret_cast<const bf16x8*>(kb + (long)(jn + l16) * 512);
    bf16x8 kn1 = *reinterpret_cast<const bf16x8*>(kb + (long)(jn + 16 + l16) * 512);
    bf16x8 vn0 = *reinterpret_cast<const bf16x8*>(vb0 + jn);
    bf16x8 vn1 = *reinterpret_cast<const bf16x8*>(vb1 + jn);
    int rn[8];
#pragma unroll
    for (int r = 0; r < 4; ++r) {
      rn[r]     = relr[(long)r * N_ + jn];
      rn[4 + r] = relr[(long)r * N_ + jn + 16];
    }

#pragma unroll
    for (int r = 0; r < 4; ++r) {
      int il = quad * 4 + r;  // this lane's C-layout row
      // fixed-max: exp(sc - FMAX). Unmasked sc ~ N(0,1): p in [e-22, e-10],
      // full bf16 relative precision; masked (-100) underflows to exact 0.
      float p0 = __expf(s0[r] * SCALE + btl[h][rv[r]] - FMAX);
      float p1 = __expf(s1[r] * SCALE + btl[h][rv[4 + r]] - FMAX);
      l_part[r] += p0 + p1;
      Pls[h][il * 40 + l16] = (bf16)p0;
      Pls[h][il * 40 + 16 + l16] = (bf16)p1;
    }
    // wave-private LDS round-trip: per-wave in-order LDS pipe, drain only
    asm volatile("s_waitcnt lgkmcnt(0)" ::: "memory");
    bf16x8 pf = *reinterpret_cast<const bf16x8*>(&Pls[h][l16 * 40 + quad * 8]);
    oacc[0] = __builtin_amdgcn_mfma_f32_16x16x32_bf16(pf, vf0, oacc[0], 0, 0, 0);
    oacc[1] = __builtin_amdgcn_mfma_f32_16x16x32_bf16(pf, vf1, oacc[1], 0, 0, 0);

    kf0 = kn0; kf1 = kn1; vf0 = vn0; vf1 = vn1;
#pragma unroll
    for (int t = 0; t < 8; ++t) rv[t] = rn[t];
  }

#pragma unroll
  for (int r = 0; r < 4; ++r) {
    float l = l_part[r];
#pragma unroll
    for (int m = 1; m < 16; m <<= 1) l += __shfl_xor(l, m);
    float inv = 1.f / l;
    long rowoff = (long)(bN + i0 + quad * 4 + r) * C_ + h * 32;
    att[rowoff + l16] = oacc[0][r] * inv;
    att[rowoff + 16 + l16] = oacc[1][r] * inv;
  }
}

// ---------------------------------------------------------------------------
// Output projection, fp32 in/out, IN-PLACE SAFE (A aliases Cm): block owns
// 16 rows exclusively, stages its full 16x256 A-stripe (fp32->bf16) into LDS
// before any write. Software-pipelined B staging. 512 blocks, 4 waves.
// ---------------------------------------------------------------------------
__global__ __launch_bounds__(256) void gemm_proj(
    const float* __restrict__ A, const float* __restrict__ Bm,
    const float* __restrict__ bias, float* __restrict__ Cm)
{
  __shared__ bf16 As[16][264];   // full K for 16 rows
  __shared__ bf16 Bts[256][40];  // per-k-tile B transposed: Bts[n][k]

  int tid = threadIdx.x;
  int wave = tid >> 6, lane = tid & 63, quad = lane >> 4, l16 = lane & 15;
  int m0 = blockIdx.x * 16;

  {
    int row = tid >> 4, c0 = (tid & 15) * 16;
#pragma unroll
    for (int j = 0; j < 4; ++j) {
      float4 v = *reinterpret_cast<const float4*>(A + (long)(m0 + row) * C_ + c0 + j * 4);
      As[row][c0 + j * 4 + 0] = (bf16)v.x;
      As[row][c0 + j * 4 + 1] = (bf16)v.y;
      As[row][c0 + j * 4 + 2] = (bf16)v.z;
      As[row][c0 + j * 4 + 3] = (bf16)v.w;
    }
  }

  f32x4 acc[4] = {};
  int bk = tid >> 3, bn0 = (tid & 7) * 32;
  const float* bptr = Bm + (long)bk * C_ + bn0;

  float4 bv[8];
#pragma unroll
  for (int j4 = 0; j4 < 8; ++j4)
    bv[j4] = *reinterpret_cast<const float4*>(bptr + j4 * 4);

  for (int k0 = 0; k0 < C_; k0 += 32) {
    __syncthreads();  // k0=0: covers As staging; later: prior Bts reads
#pragma unroll
    for (int j4 = 0; j4 < 8; ++j4) {
      Bts[bn0 + j4 * 4 + 0][bk] = (bf16)bv[j4].x;
      Bts[bn0 + j4 * 4 + 1][bk] = (bf16)bv[j4].y;
      Bts[bn0 + j4 * 4 + 2][bk] = (bf16)bv[j4].z;
      Bts[bn0 + j4 * 4 + 3][bk] = (bf16)bv[j4].w;
    }
    __syncthreads();

    int kn = k0 + 32;
    if (kn < C_) {  // uniform: prefetch next B k-tile
#pragma unroll
      for (int j4 = 0; j4 < 8; ++j4)
        bv[j4] = *reinterpret_cast<const float4*>(bptr + (long)kn * C_ + j4 * 4);
    }

    bf16x8 af = *reinterpret_cast<const bf16x8*>(&As[l16][k0 + quad * 8]);
#pragma unroll
    for (int ni = 0; ni < 4; ++ni) {
      bf16x8 bfr = *reinterpret_cast<const bf16x8*>(
          &Bts[wave * 64 + ni * 16 + l16][quad * 8]);
      acc[ni] = __builtin_amdgcn_mfma_f32_16x16x32_bf16(af, bfr, acc[ni], 0, 0, 0);
    }
  }

#pragma unroll
  for (int ni = 0; ni < 4; ++ni)
#pragma unroll
    for (int r = 0; r < 4; ++r) {
      int row = m0 + quad * 4 + r;
      int col = wave * 64 + ni * 16 + l16;
      Cm[(long)row * C_ + col] = acc[ni][r] + bias[col];
    }
}

// ---------------------------------------------------------------------------
extern "C" void kernel_launch(void* const* d_in, const int* in_sizes, int n_in,
                              void* d_out, int out_size, void* d_ws, size_t ws_size,
                              hipStream_t stream) {
  const float* X     = (const float*)d_in[0];   // att_embedding [8,1024,256] fp32
  const int*   rel   = (const int*)d_in[1];     // relation_position [8,1024,1024]
  const int*   rlen  = (const int*)d_in[2];     // rel_len [8]
  const float* Wqkv  = (const float*)d_in[3];   // [256,768] fp32
  const float* Wproj = (const float*)d_in[4];   // [256,256] fp32
  const float* bproj = (const float*)d_in[5];   // [256] fp32
  const float* btab  = (const float*)d_in[6];   // [10,8] fp32
  float* out = (float*)d_out;                   // [8,1024,256] fp32

  char* ws = (char*)d_ws;
  bf16* qk = (bf16*)ws;                                  // 8192*512 bf16 = 8.4 MB
  bf16* vT = (bf16*)(ws + (size_t)8192 * 512 * 2);       // 8*256*1024 bf16 = 4.2 MB
  // attention output (fp32) lives in d_out; gemm_proj is in-place safe.

  gemm_qkv<<<dim3(8192 / 64, C3_ / 64), 256, 0, stream>>>(X, Wqkv, qk, vT);
  flash_attn<<<dim3(N_ / 16, B_), 512, 0, stream>>>(qk, vT, rel, rlen, btab, out);
  gemm_proj<<<dim3(8192 / 16), 256, 0, stream>>>(out, Wproj, bproj, out);
}

// Round 6
// 180.229 us; speedup vs baseline: 1.0941x; 1.0941x over previous
//
#include <hip/hip_runtime.h>
#include <hip/hip_bf16.h>

typedef __bf16 bf16;
typedef __bf16 bf16x8 __attribute__((ext_vector_type(8)));
typedef float f32x4 __attribute__((ext_vector_type(4)));

#define B_ 8
#define N_ 1024
#define C_ 256
#define H_ 8
#define C3_ 768
#define SCALE 0.17677669529663689f  // 1/sqrt(32)
#define FMAX 16.0f                  // fixed softmax max; scores ~N(0,1), margin huge

// ---------------------------------------------------------------------------
// QKV projection. A = X [8192,256] fp32, Bm = W_qkv [256,768] fp32.
// fp32->bf16 during LDS staging; bf16 MFMA, fp32 accum. Software-pipelined.
// cols 0..511 (q,k) -> qk[row*512+col]; cols 512..767 (v) -> vT transposed.
// ---------------------------------------------------------------------------
__global__ __launch_bounds__(256) void gemm_qkv(
    const float* __restrict__ A, const float* __restrict__ Bm,
    bf16* __restrict__ qk, bf16* __restrict__ vT)
{
  __shared__ bf16 As[64][40];
  __shared__ bf16 Bts[64][40];  // B transposed: Bts[n][k]

  int tid = threadIdx.x;
  int wave = tid >> 6, lane = tid & 63, quad = lane >> 4, l16 = lane & 15;
  int m0 = blockIdx.x * 64, n0 = blockIdx.y * 64;
  int msub = (wave & 1) * 32, nsub = (wave >> 1) * 32;

  f32x4 acc[2][2] = {};

  int arow = tid >> 2, akc = (tid & 3) * 8;  // A stage: 64 rows x 32 k
  int bk = tid >> 3, bn8 = (tid & 7) * 8;    // B stage: 32 k x 64 n

  const float* aptr = A + (long)(m0 + arow) * C_ + akc;
  const float* bptr = Bm + (long)bk * C3_ + n0 + bn8;

  float4 a0 = *reinterpret_cast<const float4*>(aptr);
  float4 a1 = *reinterpret_cast<const float4*>(aptr + 4);
  float4 b0 = *reinterpret_cast<const float4*>(bptr);
  float4 b1 = *reinterpret_cast<const float4*>(bptr + 4);

  for (int k0 = 0; k0 < C_; k0 += 32) {
    __syncthreads();
    bf16 at[8] = {(bf16)a0.x, (bf16)a0.y, (bf16)a0.z, (bf16)a0.w,
                  (bf16)a1.x, (bf16)a1.y, (bf16)a1.z, (bf16)a1.w};
    *reinterpret_cast<bf16x8*>(&As[arow][akc]) = *reinterpret_cast<bf16x8*>(at);
    Bts[bn8 + 0][bk] = (bf16)b0.x; Bts[bn8 + 1][bk] = (bf16)b0.y;
    Bts[bn8 + 2][bk] = (bf16)b0.z; Bts[bn8 + 3][bk] = (bf16)b0.w;
    Bts[bn8 + 4][bk] = (bf16)b1.x; Bts[bn8 + 5][bk] = (bf16)b1.y;
    Bts[bn8 + 6][bk] = (bf16)b1.z; Bts[bn8 + 7][bk] = (bf16)b1.w;
    __syncthreads();

    int kn = k0 + 32;
    if (kn < C_) {
      a0 = *reinterpret_cast<const float4*>(aptr + kn);
      a1 = *reinterpret_cast<const float4*>(aptr + kn + 4);
      b0 = *reinterpret_cast<const float4*>(bptr + (long)kn * C3_);
      b1 = *reinterpret_cast<const float4*>(bptr + (long)kn * C3_ + 4);
    }

    bf16x8 af0 = *reinterpret_cast<const bf16x8*>(&As[msub + l16][quad * 8]);
    bf16x8 af1 = *reinterpret_cast<const bf16x8*>(&As[msub + 16 + l16][quad * 8]);
    bf16x8 bfr0 = *reinterpret_cast<const bf16x8*>(&Bts[nsub + l16][quad * 8]);
    bf16x8 bfr1 = *reinterpret_cast<const bf16x8*>(&Bts[nsub + 16 + l16][quad * 8]);
    acc[0][0] = __builtin_amdgcn_mfma_f32_16x16x32_bf16(af0, bfr0, acc[0][0], 0, 0, 0);
    acc[0][1] = __builtin_amdgcn_mfma_f32_16x16x32_bf16(af0, bfr1, acc[0][1], 0, 0, 0);
    acc[1][0] = __builtin_amdgcn_mfma_f32_16x16x32_bf16(af1, bfr0, acc[1][0], 0, 0, 0);
    acc[1][1] = __builtin_amdgcn_mfma_f32_16x16x32_bf16(af1, bfr1, acc[1][1], 0, 0, 0);
  }

#pragma unroll
  for (int mi = 0; mi < 2; ++mi)
#pragma unroll
    for (int ni = 0; ni < 2; ++ni)
#pragma unroll
      for (int r = 0; r < 4; ++r) {
        int row = m0 + msub + mi * 16 + quad * 4 + r;  // C layout: row=quad*4+reg
        int col = n0 + nsub + ni * 16 + l16;           // col=lane&15
        float v = acc[mi][ni][r];
        if (col < 512) {
          qk[(long)row * 512 + col] = (bf16)v;
        } else {
          int b = row >> 10, n = row & 1023;
          vT[((long)(b * C_ + (col - 512))) * N_ + n] = (bf16)v;
        }
      }
}

// ---------------------------------------------------------------------------
// Flash attention, fixed-max softmax. Block = (16-row i-tile, b), 512 thr,
// one wave per head. K-tile (32x256, all heads), V-tile (256x32) and rel
// tile staged in LDS via coalesced global loads, register-prefetched across
// the barrier pair (m97-style 2-barrier K-loop). Fragments via ds_read_b128
// from padded LDS. P via wave-private LDS (lgkmcnt drain only).
// ---------------------------------------------------------------------------
__global__ __launch_bounds__(512) void flash_attn(
    const bf16* __restrict__ qk, const bf16* __restrict__ vT,
    const int* __restrict__ rel, const int* __restrict__ rel_len,
    const float* __restrict__ btab, float* __restrict__ att)
{
  __shared__ bf16 Ks[32][264];     // K-tile: [j-row][k-channel 0..255]
  __shared__ bf16 Vs[256][40];     // V-tile: [c-channel][jj 0..31]
  __shared__ int  Rels[16][33];    // rel tile: [i-row][jj]
  __shared__ bf16 Pls[H_][16 * 40];
  __shared__ float btl[H_][16];

  int tid = threadIdx.x;
  int h = tid >> 6, lane = tid & 63, quad = lane >> 4, l16 = lane & 15;
  int b = blockIdx.y, i0 = blockIdx.x * 16;
  long bN = (long)b * N_;

  int mask_len = (int)((float)rel_len[b] * 0.5f);
  if (tid < 80) {
    int t = tid >> 3, hh = tid & 7;
    btl[hh][t] = btab[t * H_ + hh] + (t > mask_len ? -100.f : 0.f);
  }

  // Q fragment: direct global, once (scattered but amortized)
  bf16x8 qf = *reinterpret_cast<const bf16x8*>(
      qk + (bN + i0 + l16) * 512 + h * 32 + quad * 8);

  // coalesced staging assignments
  int krow = tid >> 4, koff = (tid & 15) * 16;   // 32 rows x 256 elems
  const bf16* kgp = qk + (bN + krow) * 512 + 256 + koff;       // + j0*512
  int vrow = tid >> 1, voff = (tid & 1) * 16;    // 256 rows x 32 elems
  const bf16* vgp = vT + ((long)b * C_ + vrow) * N_ + voff;    // + j0
  int rrow = tid >> 5, rcol = tid & 31;          // 16 rows x 32
  const int* rgp = rel + (bN + i0 + rrow) * N_ + rcol;         // + j0

  // pipeline preload j0 = 0
  bf16x8 kr0 = *reinterpret_cast<const bf16x8*>(kgp);
  bf16x8 kr1 = *reinterpret_cast<const bf16x8*>(kgp + 8);
  bf16x8 vr0 = *reinterpret_cast<const bf16x8*>(vgp);
  bf16x8 vr1 = *reinterpret_cast<const bf16x8*>(vgp + 8);
  int rr = *rgp;

  f32x4 oacc[2] = {};
  float l_part[4] = {0.f, 0.f, 0.f, 0.f};

  for (int j0 = 0; j0 < N_; j0 += 32) {
    __syncthreads();  // previous iteration's readers done
    *reinterpret_cast<bf16x8*>(&Ks[krow][koff]) = kr0;
    *reinterpret_cast<bf16x8*>(&Ks[krow][koff + 8]) = kr1;
    *reinterpret_cast<bf16x8*>(&Vs[vrow][voff]) = vr0;
    *reinterpret_cast<bf16x8*>(&Vs[vrow][voff + 8]) = vr1;
    Rels[rrow][rcol] = rr;
    __syncthreads();  // staged data visible

    // prefetch next tile (clamped; values unused on last iter)
    int jn = j0 + 32; jn = (jn < N_) ? jn : 0;
    kr0 = *reinterpret_cast<const bf16x8*>(kgp + (long)jn * 512);
    kr1 = *reinterpret_cast<const bf16x8*>(kgp + (long)jn * 512 + 8);
    vr0 = *reinterpret_cast<const bf16x8*>(vgp + jn);
    vr1 = *reinterpret_cast<const bf16x8*>(vgp + jn + 8);
    rr = rgp[jn];

    bf16x8 kf0 = *reinterpret_cast<const bf16x8*>(&Ks[l16][h * 32 + quad * 8]);
    bf16x8 kf1 = *reinterpret_cast<const bf16x8*>(&Ks[16 + l16][h * 32 + quad * 8]);
    f32x4 z = {};
    f32x4 s0 = __builtin_amdgcn_mfma_f32_16x16x32_bf16(qf, kf0, z, 0, 0, 0);
    f32x4 s1 = __builtin_amdgcn_mfma_f32_16x16x32_bf16(qf, kf1, z, 0, 0, 0);

#pragma unroll
    for (int r = 0; r < 4; ++r) {
      int il = quad * 4 + r;  // this lane's C-layout row
      int rv0 = Rels[il][l16];
      int rv1 = Rels[il][16 + l16];
      // fixed-max: exp(sc - FMAX). Unmasked sc ~ N(0,1): p in [e-22, e-10],
      // full bf16 relative precision; masked (-100) underflows to exact 0.
      float p0 = __expf(s0[r] * SCALE + btl[h][rv0] - FMAX);
      float p1 = __expf(s1[r] * SCALE + btl[h][rv1] - FMAX);
      l_part[r] += p0 + p1;
      Pls[h][il * 40 + l16] = (bf16)p0;
      Pls[h][il * 40 + 16 + l16] = (bf16)p1;
    }
    // wave-private LDS round-trip: per-wave in-order LDS pipe, drain only
    asm volatile("s_waitcnt lgkmcnt(0)" ::: "memory");
    bf16x8 pf = *reinterpret_cast<const bf16x8*>(&Pls[h][l16 * 40 + quad * 8]);
    bf16x8 vf0 = *reinterpret_cast<const bf16x8*>(&Vs[h * 32 + l16][quad * 8]);
    bf16x8 vf1 = *reinterpret_cast<const bf16x8*>(&Vs[h * 32 + 16 + l16][quad * 8]);
    oacc[0] = __builtin_amdgcn_mfma_f32_16x16x32_bf16(pf, vf0, oacc[0], 0, 0, 0);
    oacc[1] = __builtin_amdgcn_mfma_f32_16x16x32_bf16(pf, vf1, oacc[1], 0, 0, 0);
  }

#pragma unroll
  for (int r = 0; r < 4; ++r) {
    float l = l_part[r];
#pragma unroll
    for (int m = 1; m < 16; m <<= 1) l += __shfl_xor(l, m);
    float inv = 1.f / l;
    long rowoff = (bN + i0 + quad * 4 + r) * C_ + h * 32;
    att[rowoff + l16] = oacc[0][r] * inv;
    att[rowoff + 16 + l16] = oacc[1][r] * inv;
  }
}

// ---------------------------------------------------------------------------
// Output projection, fp32 in/out, IN-PLACE SAFE (A aliases Cm): block owns
// 16 rows exclusively, stages its full 16x256 A-stripe (fp32->bf16) into LDS
// before any write. Software-pipelined B staging. 512 blocks, 4 waves.
// ---------------------------------------------------------------------------
__global__ __launch_bounds__(256) void gemm_proj(
    const float* __restrict__ A, const float* __restrict__ Bm,
    const float* __restrict__ bias, float* __restrict__ Cm)
{
  __shared__ bf16 As[16][264];   // full K for 16 rows
  __shared__ bf16 Bts[256][40];  // per-k-tile B transposed: Bts[n][k]

  int tid = threadIdx.x;
  int wave = tid >> 6, lane = tid & 63, quad = lane >> 4, l16 = lane & 15;
  int m0 = blockIdx.x * 16;

  {
    int row = tid >> 4, c0 = (tid & 15) * 16;
#pragma unroll
    for (int j = 0; j < 4; ++j) {
      float4 v = *reinterpret_cast<const float4*>(A + (long)(m0 + row) * C_ + c0 + j * 4);
      As[row][c0 + j * 4 + 0] = (bf16)v.x;
      As[row][c0 + j * 4 + 1] = (bf16)v.y;
      As[row][c0 + j * 4 + 2] = (bf16)v.z;
      As[row][c0 + j * 4 + 3] = (bf16)v.w;
    }
  }

  f32x4 acc[4] = {};
  int bk = tid >> 3, bn0 = (tid & 7) * 32;
  const float* bptr = Bm + (long)bk * C_ + bn0;

  float4 bv[8];
#pragma unroll
  for (int j4 = 0; j4 < 8; ++j4)
    bv[j4] = *reinterpret_cast<const float4*>(bptr + j4 * 4);

  for (int k0 = 0; k0 < C_; k0 += 32) {
    __syncthreads();  // k0=0: covers As staging; later: prior Bts reads
#pragma unroll
    for (int j4 = 0; j4 < 8; ++j4) {
      Bts[bn0 + j4 * 4 + 0][bk] = (bf16)bv[j4].x;
      Bts[bn0 + j4 * 4 + 1][bk] = (bf16)bv[j4].y;
      Bts[bn0 + j4 * 4 + 2][bk] = (bf16)bv[j4].z;
      Bts[bn0 + j4 * 4 + 3][bk] = (bf16)bv[j4].w;
    }
    __syncthreads();

    int kn = k0 + 32;
    if (kn < C_) {
#pragma unroll
      for (int j4 = 0; j4 < 8; ++j4)
        bv[j4] = *reinterpret_cast<const float4*>(bptr + (long)kn * C_ + j4 * 4);
    }

    bf16x8 af = *reinterpret_cast<const bf16x8*>(&As[l16][k0 + quad * 8]);
#pragma unroll
    for (int ni = 0; ni < 4; ++ni) {
      bf16x8 bfr = *reinterpret_cast<const bf16x8*>(
          &Bts[wave * 64 + ni * 16 + l16][quad * 8]);
      acc[ni] = __builtin_amdgcn_mfma_f32_16x16x32_bf16(af, bfr, acc[ni], 0, 0, 0);
    }
  }

#pragma unroll
  for (int ni = 0; ni < 4; ++ni)
#pragma unroll
    for (int r = 0; r < 4; ++r) {
      int row = m0 + quad * 4 + r;
      int col = wave * 64 + ni * 16 + l16;
      Cm[(long)row * C_ + col] = acc[ni][r] + bias[col];
    }
}

// ---------------------------------------------------------------------------
extern "C" void kernel_launch(void* const* d_in, const int* in_sizes, int n_in,
                              void* d_out, int out_size, void* d_ws, size_t ws_size,
                              hipStream_t stream) {
  const float* X     = (const float*)d_in[0];   // att_embedding [8,1024,256] fp32
  const int*   rel   = (const int*)d_in[1];     // relation_position [8,1024,1024]
  const int*   rlen  = (const int*)d_in[2];     // rel_len [8]
  const float* Wqkv  = (const float*)d_in[3];   // [256,768] fp32
  const float* Wproj = (const float*)d_in[4];   // [256,256] fp32
  const float* bproj = (const float*)d_in[5];   // [256] fp32
  const float* btab  = (const float*)d_in[6];   // [10,8] fp32
  float* out = (float*)d_out;                   // [8,1024,256] fp32

  char* ws = (char*)d_ws;
  bf16* qk = (bf16*)ws;                                  // 8192*512 bf16 = 8.4 MB
  bf16* vT = (bf16*)(ws + (size_t)8192 * 512 * 2);       // 8*256*1024 bf16 = 4.2 MB
  // attention output (fp32) lives in d_out; gemm_proj is in-place safe.

  gemm_qkv<<<dim3(8192 / 64, C3_ / 64), 256, 0, stream>>>(X, Wqkv, qk, vT);
  flash_attn<<<dim3(N_ / 16, B_), 512, 0, stream>>>(qk, vT, rel, rlen, btab, out);
  gemm_proj<<<dim3(8192 / 16), 256, 0, stream>>>(out, Wproj, bproj, out);
}

// Round 7
// 143.107 us; speedup vs baseline: 1.3779x; 1.2594x over previous
//
#include <hip/hip_runtime.h>
#include <hip/hip_bf16.h>

typedef __bf16 bf16;
typedef __bf16 bf16x2 __attribute__((ext_vector_type(2)));
typedef __bf16 bf16x8 __attribute__((ext_vector_type(8)));
typedef float f32x4 __attribute__((ext_vector_type(4)));
typedef int i32x4 __attribute__((ext_vector_type(4)));

#define B_ 8
#define N_ 1024
#define C_ 256
#define H_ 8
#define C3_ 768
#define SCALE 0.17677669529663689f  // 1/sqrt(32)
#define FMAX 16.0f                  // fixed softmax max; scores ~N(0,1), margin huge

// ws layout (bf16 elements):
//   Wq_tiled [8 kt][12 nt][64 n][32 k]   393216 B  @ 0
//   Wp_tiled [8 kt][256 n][32 k]         131072 B  @ 393216
//   q  [8192][256]                       4 MiB     @ 524288
//   kT [b][h][1024 n][32 d]              4 MiB     @ 4718592
//   vT [b][c=h*32+d][1024 n']  (n' = perm within 32-blocks)  @ 8912896
// perm(n within 32): n' = 2*(n&15) + ((n>>4)&1)  [+ (n&~31)]

// ---------------------------------------------------------------------------
// prep: transpose + convert weights into tiled bf16 layouts (one-off, tiny).
// grid 1024 x 256 threads; first 768 blocks -> Wq_tiled, rest -> Wp_tiled.
// ---------------------------------------------------------------------------
__global__ __launch_bounds__(256) void prep(
    const float* __restrict__ Wqkv, const float* __restrict__ Wproj,
    bf16* __restrict__ Wq_tiled, bf16* __restrict__ Wp_tiled)
{
  int bb = blockIdx.x;
  int o = bb * 256 + threadIdx.x;
  if (bb < 768) {
    int kk = o & 31;
    int idx = o >> 5;
    int nr = idx & 63;
    int qq = idx >> 6;            // kt*12 + nt
    int nt = qq % 12, kt = qq / 12;
    int n = nt * 64 + nr, k = kt * 32 + kk;
    Wq_tiled[o] = (bf16)Wqkv[k * C3_ + n];
  } else {
    int p = o - 768 * 256;
    int kk = p & 31;
    int n = (p >> 5) & 255;
    int kt = p >> 13;
    int k = kt * 32 + kk;
    Wp_tiled[p] = (bf16)Wproj[k * C_ + n];
  }
}

// ---------------------------------------------------------------------------
// QKV projection. A = X [8192,256] fp32 (cvt to bf16 in staging),
// B from Wq_tiled (bf16, pre-transposed+tiled -> pure b128 copies).
// Epilogue: q cols -> q[row][col]; k cols -> kT[b][h][n][d];
// v cols -> LDS transpose (+j-perm) -> coalesced b128 stores into vT.
// ---------------------------------------------------------------------------
__global__ __launch_bounds__(256) void gemm_qkv(
    const float* __restrict__ A, const bf16* __restrict__ Wq_tiled,
    bf16* __restrict__ q, bf16* __restrict__ kT, bf16* __restrict__ vT)
{
  __shared__ bf16 As[64][40];
  __shared__ bf16 Bts[64][40];   // Bts[n][k]
  __shared__ bf16 Vls[64][72];   // v-epilogue transpose buffer

  int tid = threadIdx.x;
  int wave = tid >> 6, lane = tid & 63, quad = lane >> 4, l16 = lane & 15;
  int m0 = blockIdx.x * 64, n0 = blockIdx.y * 64;
  int msub = (wave & 1) * 32, nsub = (wave >> 1) * 32;

  f32x4 acc[2][2] = {};

  int arow = tid >> 2, akc = (tid & 3) * 8;  // A stage: 64 rows x 32 k
  const float* aptr = A + (long)(m0 + arow) * C_ + akc;
  // B stage: thread t -> nrow=t>>2, kc=(t&3)*8, one b128 from Wq_tiled
  const bf16* bptr = Wq_tiled + ((long)(blockIdx.y * 64 + (tid >> 2)) * 32 + (tid & 3) * 8);
  // per kt step: advance by 12*64*32 elems

  float4 a0 = *reinterpret_cast<const float4*>(aptr);
  float4 a1 = *reinterpret_cast<const float4*>(aptr + 4);
  i32x4 bv = *reinterpret_cast<const i32x4*>(bptr);

  for (int k0 = 0; k0 < C_; k0 += 32) {
    __syncthreads();
    bf16 at[8] = {(bf16)a0.x, (bf16)a0.y, (bf16)a0.z, (bf16)a0.w,
                  (bf16)a1.x, (bf16)a1.y, (bf16)a1.z, (bf16)a1.w};
    *reinterpret_cast<bf16x8*>(&As[arow][akc]) = *reinterpret_cast<bf16x8*>(at);
    *reinterpret_cast<i32x4*>(&Bts[tid >> 2][(tid & 3) * 8]) = bv;
    __syncthreads();

    int kn = k0 + 32;
    if (kn < C_) {
      a0 = *reinterpret_cast<const float4*>(aptr + kn);
      a1 = *reinterpret_cast<const float4*>(aptr + kn + 4);
      bv = *reinterpret_cast<const i32x4*>(bptr + (long)(kn >> 5) * (12 * 64 * 32));
    }

    bf16x8 af0 = *reinterpret_cast<const bf16x8*>(&As[msub + l16][quad * 8]);
    bf16x8 af1 = *reinterpret_cast<const bf16x8*>(&As[msub + 16 + l16][quad * 8]);
    bf16x8 bfr0 = *reinterpret_cast<const bf16x8*>(&Bts[nsub + l16][quad * 8]);
    bf16x8 bfr1 = *reinterpret_cast<const bf16x8*>(&Bts[nsub + 16 + l16][quad * 8]);
    acc[0][0] = __builtin_amdgcn_mfma_f32_16x16x32_bf16(af0, bfr0, acc[0][0], 0, 0, 0);
    acc[0][1] = __builtin_amdgcn_mfma_f32_16x16x32_bf16(af0, bfr1, acc[0][1], 0, 0, 0);
    acc[1][0] = __builtin_amdgcn_mfma_f32_16x16x32_bf16(af1, bfr0, acc[1][0], 0, 0, 0);
    acc[1][1] = __builtin_amdgcn_mfma_f32_16x16x32_bf16(af1, bfr1, acc[1][1], 0, 0, 0);
  }

  if (n0 < 512) {
    // q / k epilogue: scalar stores (16 consecutive d per quad-row: OK)
#pragma unroll
    for (int mi = 0; mi < 2; ++mi)
#pragma unroll
      for (int ni = 0; ni < 2; ++ni)
#pragma unroll
        for (int r = 0; r < 4; ++r) {
          int row = m0 + msub + mi * 16 + quad * 4 + r;
          int col = n0 + nsub + ni * 16 + l16;
          float v = acc[mi][ni][r];
          if (col < 256) {
            q[(long)row * 256 + col] = (bf16)v;
          } else {
            int b = row >> 10, n = row & 1023;
            int c = col - 256, h = c >> 5, d = c & 31;
            kT[(((long)(b * H_ + h)) * N_ + n) * 32 + d] = (bf16)v;
          }
        }
  } else {
    // v epilogue: transpose via LDS with j-permutation, coalesced stores
    __syncthreads();  // Bts/As frag reads done (paranoia; separate arrays anyway)
#pragma unroll
    for (int mi = 0; mi < 2; ++mi)
#pragma unroll
      for (int ni = 0; ni < 2; ++ni)
#pragma unroll
        for (int r = 0; r < 4; ++r) {
          int cc = nsub + ni * 16 + l16;               // channel-in-block 0..63
          int nn = msub + mi * 16 + quad * 4 + r;      // row-in-block 0..63
          int np = (nn & 32) | (2 * (nn & 15)) | ((nn >> 4) & 1);
          Vls[cc][np] = (bf16)acc[mi][ni][r];
        }
    __syncthreads();
    int cc = tid >> 2, nn8 = (tid & 3) * 16;
    int b = m0 >> 10;
    long base = ((long)(b * C_ + (n0 - 512) + cc)) * N_ + (m0 & 1023) + nn8;
    *reinterpret_cast<i32x4*>(vT + base) =
        *reinterpret_cast<const i32x4*>(&Vls[cc][nn8]);
    *reinterpret_cast<i32x4*>(vT + base + 8) =
        *reinterpret_cast<const i32x4*>(&Vls[cc][nn8 + 8]);
  }
}

// ---------------------------------------------------------------------------
// Flash attention, fixed-max softmax. Block = (16-row i-tile, b), 512 thr,
// one wave per head. K-frags direct from kT (coalesced 1KB/instr, register-
// prefetched). V staged in LDS (already j-permuted in vT). rel staged packed
// 4-rows-per-u32. P: ONE bf16x2 LDS write per lane (cols 2*l16, 2*l16+1 --
// matches vT's j-perm), b128 read back. No in-loop reductions.
// ---------------------------------------------------------------------------
__global__ __launch_bounds__(512) void flash_attn(
    const bf16* __restrict__ q, const bf16* __restrict__ kT,
    const bf16* __restrict__ vT, const int* __restrict__ rel,
    const int* __restrict__ rel_len, const float* __restrict__ btab,
    float* __restrict__ att)
{
  __shared__ bf16 Vs[256][40];     // V-tile: [c][j'] (permuted j)
  __shared__ unsigned RelsP[4][33];// packed rel: [row-group][j] 4 rows/u32
  __shared__ bf16 Pls[H_][16 * 40];
  __shared__ float btl[H_][16];

  int tid = threadIdx.x;
  int h = tid >> 6, lane = tid & 63, quad = lane >> 4, l16 = lane & 15;
  int b = blockIdx.y, i0 = blockIdx.x * 16;
  long bN = (long)b * N_;

  int mask_len = (int)((float)rel_len[b] * 0.5f);
  if (tid < 80) {
    int t = tid >> 3, hh = tid & 7;
    btl[hh][t] = btab[t * H_ + hh] + (t > mask_len ? -100.f : 0.f);
  }

  bf16x8 qf = *reinterpret_cast<const bf16x8*>(
      q + (bN + i0 + l16) * 256 + h * 32 + quad * 8);

  const bf16* kbase = kT + ((long)(b * H_ + h)) * N_ * 32 + quad * 8;  // + j*32
  int vrow = tid >> 1, voff = (tid & 1) * 16;
  const bf16* vgp = vT + ((long)b * C_ + vrow) * N_ + voff;            // + j0
  int rg = tid >> 5, rcol = tid & 31;  // valid for tid<128
  const int* rgp = rel + (bN + i0 + rg * 4) * N_ + rcol;               // + k*N + j0

  // pipeline preload j0 = 0
  bf16x8 kf0 = *reinterpret_cast<const bf16x8*>(kbase + (long)l16 * 32);
  bf16x8 kf1 = *reinterpret_cast<const bf16x8*>(kbase + (long)(16 + l16) * 32);
  bf16x8 vr0 = *reinterpret_cast<const bf16x8*>(vgp);
  bf16x8 vr1 = *reinterpret_cast<const bf16x8*>(vgp + 8);
  int rr0 = 0, rr1 = 0, rr2 = 0, rr3 = 0;
  if (tid < 128) {
    rr0 = rgp[0]; rr1 = rgp[N_]; rr2 = rgp[2 * N_]; rr3 = rgp[3 * N_];
  }

  f32x4 oacc[2] = {};
  float l_part[4] = {0.f, 0.f, 0.f, 0.f};

  for (int j0 = 0; j0 < N_; j0 += 32) {
    __syncthreads();  // previous iteration's readers done
    *reinterpret_cast<bf16x8*>(&Vs[vrow][voff]) = vr0;
    *reinterpret_cast<bf16x8*>(&Vs[vrow][voff + 8]) = vr1;
    if (tid < 128)
      RelsP[rg][rcol] = (unsigned)rr0 | ((unsigned)rr1 << 8) |
                        ((unsigned)rr2 << 16) | ((unsigned)rr3 << 24);
    __syncthreads();  // staged data visible

    // prefetch next tile (clamped; values unused on last iter)
    int jn = j0 + 32; jn = (jn < N_) ? jn : 0;
    bf16x8 kn0 = *reinterpret_cast<const bf16x8*>(kbase + (long)(jn + l16) * 32);
    bf16x8 kn1 = *reinterpret_cast<const bf16x8*>(kbase + (long)(jn + 16 + l16) * 32);
    vr0 = *reinterpret_cast<const bf16x8*>(vgp + jn);
    vr1 = *reinterpret_cast<const bf16x8*>(vgp + jn + 8);
    if (tid < 128) {
      rr0 = rgp[jn]; rr1 = rgp[N_ + jn]; rr2 = rgp[2 * N_ + jn]; rr3 = rgp[3 * N_ + jn];
    }

    f32x4 z = {};
    f32x4 s0 = __builtin_amdgcn_mfma_f32_16x16x32_bf16(qf, kf0, z, 0, 0, 0);
    f32x4 s1 = __builtin_amdgcn_mfma_f32_16x16x32_bf16(qf, kf1, z, 0, 0, 0);
    kf0 = kn0; kf1 = kn1;

    unsigned w0 = RelsP[quad][l16];
    unsigned w1 = RelsP[quad][16 + l16];
#pragma unroll
    for (int r = 0; r < 4; ++r) {
      int il = quad * 4 + r;
      int rv0 = (w0 >> (8 * r)) & 255;
      int rv1 = (w1 >> (8 * r)) & 255;
      // fixed-max: exp(sc - FMAX). Unmasked sc ~ N(0,1): full bf16 relative
      // precision; masked (-100) underflows to exact 0.
      float p0 = __expf(s0[r] * SCALE + btl[h][rv0] - FMAX);
      float p1 = __expf(s1[r] * SCALE + btl[h][rv1] - FMAX);
      l_part[r] += p0 + p1;
      bf16x2 pp = {(bf16)p0, (bf16)p1};  // cols 2*l16, 2*l16+1 (j-perm)
      *reinterpret_cast<bf16x2*>(&Pls[h][il * 40 + l16 * 2]) = pp;
    }
    // wave-private LDS round-trip: per-wave in-order LDS pipe, drain only
    asm volatile("s_waitcnt lgkmcnt(0)" ::: "memory");
    bf16x8 pf = *reinterpret_cast<const bf16x8*>(&Pls[h][l16 * 40 + quad * 8]);
    bf16x8 vf0 = *reinterpret_cast<const bf16x8*>(&Vs[h * 32 + l16][quad * 8]);
    bf16x8 vf1 = *reinterpret_cast<const bf16x8*>(&Vs[h * 32 + 16 + l16][quad * 8]);
    oacc[0] = __builtin_amdgcn_mfma_f32_16x16x32_bf16(pf, vf0, oacc[0], 0, 0, 0);
    oacc[1] = __builtin_amdgcn_mfma_f32_16x16x32_bf16(pf, vf1, oacc[1], 0, 0, 0);
  }

#pragma unroll
  for (int r = 0; r < 4; ++r) {
    float l = l_part[r];
#pragma unroll
    for (int m = 1; m < 16; m <<= 1) l += __shfl_xor(l, m);
    float inv = 1.f / l;
    long rowoff = (bN + i0 + quad * 4 + r) * C_ + h * 32;
    att[rowoff + l16] = oacc[0][r] * inv;
    att[rowoff + 16 + l16] = oacc[1][r] * inv;
  }
}

// ---------------------------------------------------------------------------
// Output projection, fp32 in/out, IN-PLACE SAFE (A aliases Cm): block owns
// 16 rows exclusively, stages its full 16x256 A-stripe (fp32->bf16) into LDS
// before any write. B from Wp_tiled: pure b128 copies. 512 blocks, 4 waves.
// ---------------------------------------------------------------------------
__global__ __launch_bounds__(256) void gemm_proj(
    const float* __restrict__ A, const bf16* __restrict__ Wp_tiled,
    const float* __restrict__ bias, float* __restrict__ Cm)
{
  __shared__ bf16 As[16][264];   // full K for 16 rows
  __shared__ bf16 Bts[256][40];  // per-k-tile B: Bts[n][k]

  int tid = threadIdx.x;
  int wave = tid >> 6, lane = tid & 63, quad = lane >> 4, l16 = lane & 15;
  int m0 = blockIdx.x * 16;

  {
    int row = tid >> 4, c0 = (tid & 15) * 16;
#pragma unroll
    for (int j8 = 0; j8 < 2; ++j8) {
      float4 v0 = *reinterpret_cast<const float4*>(A + (long)(m0 + row) * C_ + c0 + j8 * 8);
      float4 v1 = *reinterpret_cast<const float4*>(A + (long)(m0 + row) * C_ + c0 + j8 * 8 + 4);
      bf16 at[8] = {(bf16)v0.x, (bf16)v0.y, (bf16)v0.z, (bf16)v0.w,
                    (bf16)v1.x, (bf16)v1.y, (bf16)v1.z, (bf16)v1.w};
      *reinterpret_cast<bf16x8*>(&As[row][c0 + j8 * 8]) = *reinterpret_cast<bf16x8*>(at);
    }
  }

  f32x4 acc[4] = {};
  const bf16* wp = Wp_tiled + (long)tid * 32;  // + kt*8192

  i32x4 bv0 = *reinterpret_cast<const i32x4*>(wp);
  i32x4 bv1 = *reinterpret_cast<const i32x4*>(wp + 8);
  i32x4 bv2 = *reinterpret_cast<const i32x4*>(wp + 16);
  i32x4 bv3 = *reinterpret_cast<const i32x4*>(wp + 24);

  for (int k0 = 0; k0 < C_; k0 += 32) {
    __syncthreads();  // k0=0: covers As staging; later: prior Bts reads
    *reinterpret_cast<i32x4*>(&Bts[tid][0]) = bv0;
    *reinterpret_cast<i32x4*>(&Bts[tid][8]) = bv1;
    *reinterpret_cast<i32x4*>(&Bts[tid][16]) = bv2;
    *reinterpret_cast<i32x4*>(&Bts[tid][24]) = bv3;
    __syncthreads();

    int kn = k0 + 32;
    if (kn < C_) {
      long off = (long)(kn >> 5) * 8192;
      bv0 = *reinterpret_cast<const i32x4*>(wp + off);
      bv1 = *reinterpret_cast<const i32x4*>(wp + off + 8);
      bv2 = *reinterpret_cast<const i32x4*>(wp + off + 16);
      bv3 = *reinterpret_cast<const i32x4*>(wp + off + 24);
    }

    bf16x8 af = *reinterpret_cast<const bf16x8*>(&As[l16][k0 + quad * 8]);
#pragma unroll
    for (int ni = 0; ni < 4; ++ni) {
      bf16x8 bfr = *reinterpret_cast<const bf16x8*>(
          &Bts[wave * 64 + ni * 16 + l16][quad * 8]);
      acc[ni] = __builtin_amdgcn_mfma_f32_16x16x32_bf16(af, bfr, acc[ni], 0, 0, 0);
    }
  }

#pragma unroll
  for (int ni = 0; ni < 4; ++ni)
#pragma unroll
    for (int r = 0; r < 4; ++r) {
      int row = m0 + quad * 4 + r;
      int col = wave * 64 + ni * 16 + l16;
      Cm[(long)row * C_ + col] = acc[ni][r] + bias[col];
    }
}

// ---------------------------------------------------------------------------
extern "C" void kernel_launch(void* const* d_in, const int* in_sizes, int n_in,
                              void* d_out, int out_size, void* d_ws, size_t ws_size,
                              hipStream_t stream) {
  const float* X     = (const float*)d_in[0];   // att_embedding [8,1024,256] fp32
  const int*   rel   = (const int*)d_in[1];     // relation_position [8,1024,1024]
  const int*   rlen  = (const int*)d_in[2];     // rel_len [8]
  const float* Wqkv  = (const float*)d_in[3];   // [256,768] fp32
  const float* Wproj = (const float*)d_in[4];   // [256,256] fp32
  const float* bproj = (const float*)d_in[5];   // [256] fp32
  const float* btab  = (const float*)d_in[6];   // [10,8] fp32
  float* out = (float*)d_out;                   // [8,1024,256] fp32

  char* ws = (char*)d_ws;
  bf16* Wq_tiled = (bf16*)ws;                            // 393216 B
  bf16* Wp_tiled = (bf16*)(ws + 393216);                 // 131072 B
  bf16* q  = (bf16*)(ws + 524288);                       // 4 MiB
  bf16* kT = (bf16*)(ws + 524288 + 4194304);             // 4 MiB
  bf16* vT = (bf16*)(ws + 524288 + 2 * 4194304);         // 4 MiB
  // attention output (fp32) lives in d_out; gemm_proj is in-place safe.

  prep<<<dim3(1024), 256, 0, stream>>>(Wqkv, Wproj, Wq_tiled, Wp_tiled);
  gemm_qkv<<<dim3(8192 / 64, C3_ / 64), 256, 0, stream>>>(X, Wq_tiled, q, kT, vT);
  flash_attn<<<dim3(N_ / 16, B_), 512, 0, stream>>>(q, kT, vT, rel, rlen, btab, out);
  gemm_proj<<<dim3(8192 / 16), 256, 0, stream>>>(out, Wp_tiled, bproj, out);
}